// Round 2
// baseline (884.205 us; speedup 1.0000x reference)
//
#include <hip/hip_runtime.h>
#include <math.h>

#define HW 4096
#define CCH 256
#define DQK 32
#define QB 64
#define JB 64

typedef __attribute__((ext_vector_type(8))) short bf16x8;
typedef __attribute__((ext_vector_type(4))) float f32x4;

__device__ __forceinline__ ushort f2bf(float f) {
    union { float f; unsigned u; } v; v.f = f;
    unsigned u = v.u;
    unsigned r = u + 0x7fffu + ((u >> 16) & 1u);   // round-to-nearest-even
    return (ushort)(r >> 16);
}

// ---------------------------------------------------------------------------
// K0: x (fp32) -> xbf (bf16), same [B][C][HW] layout. 4M elems.
// ---------------------------------------------------------------------------
__global__ __launch_bounds__(256) void x2bf_kernel(
    const float* __restrict__ x, ushort* __restrict__ xbf)
{
    size_t i = ((size_t)blockIdx.x * 256 + threadIdx.x) * 4;
    float4 v = *(const float4*)(x + i);
    ushort4 o = make_ushort4(f2bf(v.x), f2bf(v.y), f2bf(v.z), f2bf(v.w));
    *(ushort4*)(xbf + i) = o;
}

// ---------------------------------------------------------------------------
// K1: q = Wq x + bq, k = Wk x + bk   (1x1 conv, 32 out-channels each)
// ---------------------------------------------------------------------------
__global__ __launch_bounds__(256) void qk_kernel(
    const float* __restrict__ x,
    const float* __restrict__ Wq, const float* __restrict__ bq,
    const float* __restrict__ Wk, const float* __restrict__ bk,
    float* __restrict__ qout, float* __restrict__ kout)
{
    const float* W    = blockIdx.y ? Wk : Wq;
    const float* bias = blockIdx.y ? bk : bq;
    float* out        = blockIdx.y ? kout : qout;

    int g = blockIdx.x * 256 + threadIdx.x;   // global pixel over B*HW
    int b = g >> 12;
    int p = g & (HW - 1);
    const float* xb = x + (size_t)b * CCH * HW + p;

    float acc[DQK];
#pragma unroll
    for (int o = 0; o < DQK; ++o) acc[o] = bias[o];

    for (int c0 = 0; c0 < CCH; c0 += 16) {
        float xv[16];
#pragma unroll
        for (int cc = 0; cc < 16; ++cc) xv[cc] = xb[(size_t)(c0 + cc) * HW];
#pragma unroll
        for (int o = 0; o < DQK; ++o) {
#pragma unroll
            for (int cc = 0; cc < 16; ++cc)
                acc[o] = fmaf(W[o * CCH + c0 + cc], xv[cc], acc[o]);
        }
    }
#pragma unroll
    for (int o = 0; o < DQK; ++o)
        out[((size_t)b * DQK + o) * HW + p] = acc[o];
}

// ---------------------------------------------------------------------------
// K2: Wov = Wo x Wv (256x256), bov = Wo bv + bo   (V/O conv folding)
// ---------------------------------------------------------------------------
__global__ __launch_bounds__(256) void wov_kernel(
    const float* __restrict__ Wo, const float* __restrict__ Wv,
    const float* __restrict__ bv, const float* __restrict__ bo,
    float* __restrict__ Wov, float* __restrict__ bov)
{
    int o = blockIdx.x;
    int c = threadIdx.x;
    float acc = 0.f;
#pragma unroll 8
    for (int m = 0; m < CCH; ++m)
        acc = fmaf(Wo[o * CCH + m], Wv[m * CCH + c], acc);
    Wov[o * CCH + c] = acc;

    __shared__ float red[256];
    red[c] = Wo[o * CCH + c] * bv[c];
    __syncthreads();
    for (int s = 128; s > 0; s >>= 1) {
        if (c < s) red[c] += red[c + s];
        __syncthreads();
    }
    if (c == 0) bov[o] = red[0] + bo[0 * CCH + o];
}

// ---------------------------------------------------------------------------
// K3: flash attention applied directly to x:
//   attnx[b,c,i] = sum_j softmax_j(q_i . k_j [masked]) * x[b,c,j]
// Scores + softmax: exact fp32 VALU (unchanged from baseline).
// PV: bf16 MFMA. D[m=c',n=i'] = A[x tile] x B[P^T]:
//   A-frag: m=lane&15, k=8*(lane>>4)+e  -> 16B global loads from xbf rows
//   B-frag: n=lane&15, k=8*(lane>>4)+e  -> pbs[i][j] row-major bf16, XOR-swz
//   C-frag: n=lane&15, m=4*(lane>>4)+reg   [m89-verified]
// One block = one (batch, 64-query tile); XCD-swizzled so each XCD reads
// exactly one batch's 2MB xbf slice (per-XCD L2 fit).
// ---------------------------------------------------------------------------
__global__ __launch_bounds__(256) void attn_kernel(
    const float* __restrict__ q, const float* __restrict__ k,
    const ushort* __restrict__ xbf, const float* __restrict__ mask,
    float* __restrict__ attnx)
{
    __shared__ float qs[DQK][QB];               // 8 KB
    __shared__ float ks[DQK][JB];               // 8 KB
    __shared__ float ps[QB][JB + 4];            // 17 KB fp32 scores
    __shared__ __align__(16) ushort pbs[QB * JB]; // 8 KB bf16 P, XOR-swizzled
    __shared__ float ms[QB], ls[QB], fs[QB];
    __shared__ float msj[JB];

    const int t    = threadIdx.x;
    const int lane = t & 63;
    const int w    = t >> 6;        // wave id 0..3 -> channel group
    const int tc   = t & 15;        // score-phase col group
    const int ti   = t >> 4;        // score-phase row group
    const int lm   = lane & 15;     // MFMA: A-row / B-col / C-col
    const int lg   = lane >> 4;     // MFMA: k-group / C-row group

    // XCD swizzle: xcd = n%8 owns one batch (2 XCDs/batch, 32 i-tiles each)
    const int n  = blockIdx.x;
    const int b  = (n & 7) >> 1;
    const int i0 = ((n >> 3) + 32 * (n & 1)) * QB;

    const float*  qb = q    + (size_t)b * DQK * HW;
    const float*  kb = k    + (size_t)b * DQK * HW;
    const ushort* xb = xbf  + (size_t)b * CCH * HW;
    const float*  mb = mask + (size_t)b * HW;

    // load Q tile
    for (int r = t; r < DQK * QB; r += 256) {
        int d = r >> 6, ii = r & 63;
        qs[d][ii] = qb[(size_t)d * HW + i0 + ii];
    }
    if (t < QB) { ms[t] = -INFINITY; ls[t] = 0.f; }
    const float mi_r = ((t & 3) == 0) ? mb[i0 + (t >> 2)] : 0.f;

    f32x4 acc[4][4];
#pragma unroll
    for (int cf = 0; cf < 4; ++cf)
#pragma unroll
        for (int fi = 0; fi < 4; ++fi) acc[cf][fi] = (f32x4){0.f, 0.f, 0.f, 0.f};

    __syncthreads();

    for (int j0 = 0; j0 < HW; j0 += JB) {
        // --- issue A-frag loads early: hidden under the fp32 score phase ---
        bf16x8 afr[4][2];
#pragma unroll
        for (int cf = 0; cf < 4; ++cf)
#pragma unroll
            for (int ks2 = 0; ks2 < 2; ++ks2)
                afr[cf][ks2] = *(const bf16x8*)(xb +
                    (size_t)(64 * w + 16 * cf + lm) * HW + j0 + 32 * ks2 + 8 * lg);

        // --- stage K tile + mask slice ---
        for (int r = t; r < DQK * JB; r += 256) {
            int d = r >> 6, jj = r & 63;
            ks[d][jj] = kb[(size_t)d * HW + j0 + jj];
        }
        if (t < JB) msj[t] = mb[j0 + t];
        __syncthreads();

        // --- scores (exact fp32): rows ti*4+a, cols tc*4+e ---
        float s00=0,s01=0,s02=0,s03=0, s10=0,s11=0,s12=0,s13=0;
        float s20=0,s21=0,s22=0,s23=0, s30=0,s31=0,s32=0,s33=0;
#pragma unroll
        for (int d = 0; d < DQK; ++d) {
            float4 qf = *(const float4*)&qs[d][ti * 4];
            float4 kf = *(const float4*)&ks[d][tc * 4];
            s00 = fmaf(qf.x, kf.x, s00); s01 = fmaf(qf.x, kf.y, s01);
            s02 = fmaf(qf.x, kf.z, s02); s03 = fmaf(qf.x, kf.w, s03);
            s10 = fmaf(qf.y, kf.x, s10); s11 = fmaf(qf.y, kf.y, s11);
            s12 = fmaf(qf.y, kf.z, s12); s13 = fmaf(qf.y, kf.w, s13);
            s20 = fmaf(qf.z, kf.x, s20); s21 = fmaf(qf.z, kf.y, s21);
            s22 = fmaf(qf.z, kf.z, s22); s23 = fmaf(qf.z, kf.w, s23);
            s30 = fmaf(qf.w, kf.x, s30); s31 = fmaf(qf.w, kf.y, s31);
            s32 = fmaf(qf.w, kf.z, s32); s33 = fmaf(qf.w, kf.w, s33);
        }
        *(float4*)&ps[ti * 4 + 0][tc * 4] = make_float4(s00, s01, s02, s03);
        *(float4*)&ps[ti * 4 + 1][tc * 4] = make_float4(s10, s11, s12, s13);
        *(float4*)&ps[ti * 4 + 2][tc * 4] = make_float4(s20, s21, s22, s23);
        *(float4*)&ps[ti * 4 + 3][tc * 4] = make_float4(s30, s31, s32, s33);
        __syncthreads();

        // --- online softmax (fp32), one row per thread; emit bf16 P ---
        if ((t & 3) == 0) {
            const int i = t >> 2;
            const float mi = mi_r;
            const float mold = ms[i];
            float mrow = -INFINITY;
#pragma unroll
            for (int jq = 0; jq < 16; ++jq) {
                float4 sv = *(const float4*)&ps[i][jq * 4];
                float4 mj = *(const float4*)&msj[jq * 4];
                float vx = (mi * mj.x == 0.f) ? -INFINITY : sv.x * mi * mj.x;
                float vy = (mi * mj.y == 0.f) ? -INFINITY : sv.y * mi * mj.y;
                float vz = (mi * mj.z == 0.f) ? -INFINITY : sv.z * mi * mj.z;
                float vw = (mi * mj.w == 0.f) ? -INFINITY : sv.w * mi * mj.w;
                *(float4*)&ps[i][jq * 4] = make_float4(vx, vy, vz, vw);
                mrow = fmaxf(mrow, fmaxf(fmaxf(vx, vy), fmaxf(vz, vw)));
            }
            const float mnew = fmaxf(mold, mrow);
            const float fcorr = __expf(mold - mnew);  // first tile: exp(-inf)=0
            const int swz = (i & 7) << 3;
            float sum = 0.f;
#pragma unroll
            for (int jq = 0; jq < 16; ++jq) {
                float4 sv = *(const float4*)&ps[i][jq * 4];
                float px = __expf(sv.x - mnew);
                float py = __expf(sv.y - mnew);
                float pz = __expf(sv.z - mnew);
                float pw = __expf(sv.w - mnew);
                sum += px + py + pz + pw;
                ushort4 pk = make_ushort4(f2bf(px), f2bf(py), f2bf(pz), f2bf(pw));
                *(ushort4*)&pbs[i * 64 + ((jq * 4) ^ swz)] = pk;
            }
            ms[i] = mnew;
            ls[i] = ls[i] * fcorr + sum;
            fs[i] = fcorr;
        }
        __syncthreads();

        // --- rescale accumulators (factor depends on col i = 16*fi + lm) ---
        float fcol[4];
#pragma unroll
        for (int fi = 0; fi < 4; ++fi) fcol[fi] = fs[16 * fi + lm];
#pragma unroll
        for (int cf = 0; cf < 4; ++cf)
#pragma unroll
            for (int fi = 0; fi < 4; ++fi) acc[cf][fi] *= fcol[fi];

        // --- B-frags from swizzled P, then MFMA ---
        bf16x8 bfr[4][2];
#pragma unroll
        for (int fi = 0; fi < 4; ++fi)
#pragma unroll
            for (int ks2 = 0; ks2 < 2; ++ks2) {
                int i = 16 * fi + lm;
                int jj = 32 * ks2 + 8 * lg;
                bfr[fi][ks2] = *(const bf16x8*)&pbs[i * 64 + (jj ^ ((i & 7) << 3))];
            }
#pragma unroll
        for (int ks2 = 0; ks2 < 2; ++ks2)
#pragma unroll
            for (int cf = 0; cf < 4; ++cf)
#pragma unroll
                for (int fi = 0; fi < 4; ++fi)
                    acc[cf][fi] = __builtin_amdgcn_mfma_f32_16x16x32_bf16(
                        afr[cf][ks2], bfr[fi][ks2], acc[cf][fi], 0, 0, 0);

        __syncthreads();   // protect ks/ps/pbs/msj before next tile
    }

    // --- epilogue: divide by row sums, store (C-frag layout) ---
    float linv[4];
#pragma unroll
    for (int fi = 0; fi < 4; ++fi) linv[fi] = 1.f / ls[16 * fi + lm];
#pragma unroll
    for (int cf = 0; cf < 4; ++cf) {
#pragma unroll
        for (int fi = 0; fi < 4; ++fi) {
#pragma unroll
            for (int r = 0; r < 4; ++r) {
                int c = 64 * w + 16 * cf + 4 * lg + r;
                attnx[((size_t)b * CCH + c) * HW + i0 + 16 * fi + lm] =
                    acc[cf][fi][r] * linv[fi];
            }
        }
    }
}

// ---------------------------------------------------------------------------
// K4: pre = Wov attnx + bov; o2 = gamma*pre + x; LayerNorm over channels.
// ---------------------------------------------------------------------------
__global__ __launch_bounds__(256) void final_kernel(
    const float* __restrict__ attnx, const float* __restrict__ Wov,
    const float* __restrict__ bov, const float* __restrict__ x,
    const float* __restrict__ gamma, const float* __restrict__ ln_w,
    const float* __restrict__ ln_b, float* __restrict__ out)
{
    const int t = threadIdx.x;
    const int psub = t & 63;
    const int og = t >> 6;           // 0..3, wave-uniform
    const int g0 = blockIdx.x * 64;
    const int b = g0 >> 12;
    const int p = (g0 & (HW - 1)) + psub;

    const float* ab = attnx + (size_t)b * CCH * HW + p;
    const float* xb = x + (size_t)b * CCH * HW + p;

    float acc[64];
#pragma unroll
    for (int oo = 0; oo < 64; ++oo) acc[oo] = bov[og * 64 + oo];

    for (int c0 = 0; c0 < CCH; c0 += 8) {
        float av[8];
#pragma unroll
        for (int cc = 0; cc < 8; ++cc) av[cc] = ab[(size_t)(c0 + cc) * HW];
#pragma unroll
        for (int oo = 0; oo < 64; ++oo) {
#pragma unroll
            for (int cc = 0; cc < 8; ++cc)
                acc[oo] = fmaf(Wov[(og * 64 + oo) * CCH + c0 + cc], av[cc], acc[oo]);
        }
    }

    const float gam = gamma[0];
    float s1 = 0.f, s2 = 0.f;
#pragma unroll
    for (int oo = 0; oo < 64; ++oo) {
        float v = fmaf(gam, acc[oo], xb[(size_t)(og * 64 + oo) * HW]);
        acc[oo] = v;
        s1 += v;
        s2 = fmaf(v, v, s2);
    }

    __shared__ float r1[4][64], r2[4][64];
    r1[og][psub] = s1;
    r2[og][psub] = s2;
    __syncthreads();
    if (og == 0) {
        float a  = r1[0][psub] + r1[1][psub] + r1[2][psub] + r1[3][psub];
        float q2 = r2[0][psub] + r2[1][psub] + r2[2][psub] + r2[3][psub];
        float mu = a * (1.f / CCH);
        float var = q2 * (1.f / CCH) - mu * mu;
        r1[0][psub] = mu;
        r2[0][psub] = 1.f / sqrtf(var + 1e-5f);
    }
    __syncthreads();
    const float mu = r1[0][psub];
    const float rstd = r2[0][psub];
#pragma unroll
    for (int oo = 0; oo < 64; ++oo) {
        const int o = og * 64 + oo;
        float v = (acc[oo] - mu) * rstd * ln_w[o] + ln_b[o];
        out[((size_t)b * CCH + o) * HW + p] = v;
    }
}

// ---------------------------------------------------------------------------
extern "C" void kernel_launch(void* const* d_in, const int* in_sizes, int n_in,
                              void* d_out, int out_size, void* d_ws, size_t ws_size,
                              hipStream_t stream)
{
    const float* x     = (const float*)d_in[0];
    const float* mask  = (const float*)d_in[1];
    const float* Wq    = (const float*)d_in[2];
    const float* bq    = (const float*)d_in[3];
    const float* Wk    = (const float*)d_in[4];
    const float* bk    = (const float*)d_in[5];
    const float* Wv    = (const float*)d_in[6];
    const float* bv    = (const float*)d_in[7];
    const float* Wo    = (const float*)d_in[8];
    const float* bo    = (const float*)d_in[9];
    const float* gamma = (const float*)d_in[10];
    const float* ln_w  = (const float*)d_in[11];
    const float* ln_b  = (const float*)d_in[12];
    float* out = (float*)d_out;

    // workspace (floats unless noted): q | k | attnx | Wov | bov | xbf(bf16)
    float* q     = (float*)d_ws;
    float* kk    = q + (size_t)4 * DQK * HW;          // +2 MB
    float* attnx = kk + (size_t)4 * DQK * HW;         // +2 MB
    float* Wov   = attnx + (size_t)4 * CCH * HW;      // +16 MB
    float* bov   = Wov + CCH * CCH;                   // +256 KB
    ushort* xbf  = (ushort*)(bov + 1024);             // +8 MB  (~28.3 MB total)

    x2bf_kernel<<<4096, 256, 0, stream>>>(x, xbf);
    qk_kernel<<<dim3(64, 2), 256, 0, stream>>>(x, Wq, bq, Wk, bk, q, kk);
    wov_kernel<<<256, 256, 0, stream>>>(Wo, Wv, bv, bo, Wov, bov);
    attn_kernel<<<256, 256, 0, stream>>>(q, kk, xbf, mask, attnx);
    final_kernel<<<256, 256, 0, stream>>>(attnx, Wov, bov, x, gamma, ln_w, ln_b, out);
}

// Round 5
// 406.228 us; speedup vs baseline: 2.1766x; 2.1766x over previous
//
#include <hip/hip_runtime.h>
#include <math.h>

#define HW 4096
#define CCH 256
#define DQK 32
#define QB 64
#define JB 64
#define NT (HW / JB)

typedef __attribute__((ext_vector_type(8))) short bf16x8;
typedef __attribute__((ext_vector_type(4))) float f32x4;

__device__ __forceinline__ ushort f2bf(float f) {
    union { float f; unsigned u; } v; v.f = f;
    unsigned u = v.u;
    unsigned r = u + 0x7fffu + ((u >> 16) & 1u);   // round-to-nearest-even
    return (ushort)(r >> 16);
}
__device__ __forceinline__ float bf2f(ushort h) {
    union { unsigned u; float f; } v; v.u = ((unsigned)h) << 16;
    return v.f;
}

// ---------------------------------------------------------------------------
// K0: x (fp32) -> xbf (bf16), same [B][C][HW] layout.
// ---------------------------------------------------------------------------
__global__ __launch_bounds__(256) void x2bf_kernel(
    const float* __restrict__ x, ushort* __restrict__ xbf)
{
    size_t i = ((size_t)blockIdx.x * 256 + threadIdx.x) * 4;
    float4 v = *(const float4*)(x + i);
    ushort4 o = make_ushort4(f2bf(v.x), f2bf(v.y), f2bf(v.z), f2bf(v.w));
    *(ushort4*)(xbf + i) = o;
}

// ---------------------------------------------------------------------------
// K1: qT/kT in hi+lo bf16, layout [B*HW][32].
// grid (256, 2): y=0 -> q, y=1 -> k. Block = 64 pixels x 4 c-quarters.
// red padded to DQK+1: bank = (p+o) mod 32 -> conflict-free (was 64-way).
// ---------------------------------------------------------------------------
__global__ __launch_bounds__(256) void qkhl_kernel(
    const float* __restrict__ x,
    const float* __restrict__ Wq, const float* __restrict__ bq,
    const float* __restrict__ Wk, const float* __restrict__ bk,
    ushort* __restrict__ qth, ushort* __restrict__ qtl,
    ushort* __restrict__ kth, ushort* __restrict__ ktl)
{
    const float* W    = blockIdx.y ? Wk : Wq;
    const float* bias = blockIdx.y ? bk : bq;
    ushort* outh      = blockIdx.y ? kth : qth;
    ushort* outl      = blockIdx.y ? ktl : qtl;

    const int t  = threadIdx.x;
    const int p  = t & 63;
    const int cq = t >> 6;                 // wave-uniform c-quarter
    const int g0 = blockIdx.x * 64;        // block spans one batch (64 | 4096)
    const int b  = g0 >> 12;
    const int pp = (g0 & (HW - 1)) + p;
    const float* xb = x + (size_t)b * CCH * HW + pp;

    float acc[DQK];
#pragma unroll
    for (int o = 0; o < DQK; ++o) acc[o] = 0.f;

    for (int c0 = 64 * cq; c0 < 64 * cq + 64; c0 += 8) {
        float xv[8];
#pragma unroll
        for (int cc = 0; cc < 8; ++cc) xv[cc] = xb[(size_t)(c0 + cc) * HW];
#pragma unroll
        for (int o = 0; o < DQK; ++o)
#pragma unroll
            for (int cc = 0; cc < 8; ++cc)
                acc[o] = fmaf(W[o * CCH + c0 + cc], xv[cc], acc[o]);
    }

    __shared__ float red[4][64][DQK + 1];  // ~34 KB, +1 pad kills conflicts
#pragma unroll
    for (int o = 0; o < DQK; ++o) red[cq][p][o] = acc[o];
    __syncthreads();

    // thread t: pixel pr = t&63, out-group o8 = t>>6 (8 outs)
    const int pr = t & 63;
    const int o8 = t >> 6;
    ushort hv[8], lv[8];
#pragma unroll
    for (int oo = 0; oo < 8; ++oo) {
        const int o = o8 * 8 + oo;
        float s = red[0][pr][o] + red[1][pr][o] + red[2][pr][o] + red[3][pr][o]
                + bias[o];
        ushort h = f2bf(s);
        hv[oo] = h;
        lv[oo] = f2bf(s - bf2f(h));
    }
    const size_t g = (size_t)(g0 + pr) * DQK + o8 * 8;
    *(ushort4*)(outh + g)     = make_ushort4(hv[0], hv[1], hv[2], hv[3]);
    *(ushort4*)(outh + g + 4) = make_ushort4(hv[4], hv[5], hv[6], hv[7]);
    *(ushort4*)(outl + g)     = make_ushort4(lv[0], lv[1], lv[2], lv[3]);
    *(ushort4*)(outl + g + 4) = make_ushort4(lv[4], lv[5], lv[6], lv[7]);
}

// ---------------------------------------------------------------------------
// K2: Wov = Wo x Wv (256x256), bov = Wo bv + bo
// ---------------------------------------------------------------------------
__global__ __launch_bounds__(256) void wov_kernel(
    const float* __restrict__ Wo, const float* __restrict__ Wv,
    const float* __restrict__ bv, const float* __restrict__ bo,
    float* __restrict__ Wov, float* __restrict__ bov)
{
    int o = blockIdx.x;
    int c = threadIdx.x;
    float acc = 0.f;
#pragma unroll 8
    for (int m = 0; m < CCH; ++m)
        acc = fmaf(Wo[o * CCH + m], Wv[m * CCH + c], acc);
    Wov[o * CCH + c] = acc;

    __shared__ float red[256];
    red[c] = Wo[o * CCH + c] * bv[c];
    __syncthreads();
    for (int s = 128; s > 0; s >>= 1) {
        if (c < s) red[c] += red[c + s];
        __syncthreads();
    }
    if (c == 0) bov[o] = red[0] + bo[o];
}

// ---------------------------------------------------------------------------
// K3: flash attention on x (V/O folded). 512 threads = 8 waves, grid 256.
// Scores: MFMA with hi/lo bf16 split (fp32-grade):
//   S[j][i]: A = kT rows j, B = qT rows i, K = d = 32.
//   C-frag: lane holds S[j = 16mf+4lg+r][i = 16ib+lm]   (HW-validated r1)
// K-frags for tile jt+1 prefetched during tile jt's softmax (hides L2 lat).
// Masking done IN PLACE in sc[] (keeps score-wave live set < 128 VGPR, the
// __launch_bounds__(512,2) cap — no spills).
// Softmax: all-lane; row-reduce over j via shfl_xor(16/32). Waves 0-3 only.
// PV: all 8 waves, c-split: wave w owns c in [32w, 32w+32).
//   A = xbf rows c (16B global loads), B = P from LDS (XOR-swizzled), K = j.
// One __syncthreads per j-tile (pbs/fs double-buffered; barrier at jt+1
// orders tile jt's P reads before tile jt+2's P writes -> race-free).
// ---------------------------------------------------------------------------
__global__ __launch_bounds__(512, 2) void attn3_kernel(
    const ushort* __restrict__ qth, const ushort* __restrict__ qtl,
    const ushort* __restrict__ kth, const ushort* __restrict__ ktl,
    const ushort* __restrict__ xbf, const float* __restrict__ mask,
    float* __restrict__ attnx)
{
    __shared__ __align__(16) ushort pbs[2][QB * JB];  // 16 KB bf16 P, swizzled
    __shared__ float fs2[2][QB];
    __shared__ float lsb[QB];

    const int t    = threadIdx.x;
    const int w    = t >> 6;
    const int lane = t & 63;
    const int lm   = lane & 15;
    const int lg   = lane >> 4;
    const int ib   = w & 3;

    // XCD swizzle: each XCD pair owns one batch (xbf slice 2MB -> L2-resident)
    const int n  = blockIdx.x;
    const int b  = (n & 7) >> 1;
    const int i0 = ((n >> 3) + 32 * (n & 1)) * QB;

    const ushort* xb = xbf  + (size_t)b * CCH * HW;
    const float*  mb = mask + (size_t)b * HW;

    // q B-frags (hi/lo) for this wave's i-block — loaded once
    bf16x8 qh, ql;
    {
        const size_t qr = ((size_t)(b * HW + i0 + 16 * ib + lm)) * DQK + 8 * lg;
        qh = *(const bf16x8*)(qth + qr);
        ql = *(const bf16x8*)(qtl + qr);
    }
    const float mi = mb[i0 + 16 * ib + lm];
    float mreg = -INFINITY, lreg = 0.f;

    f32x4 acc[2][4];
#pragma unroll
    for (int cf = 0; cf < 2; ++cf)
#pragma unroll
        for (int fi = 0; fi < 4; ++fi) acc[cf][fi] = (f32x4){0.f, 0.f, 0.f, 0.f};

    // preload K-frags for tile 0
    bf16x8 kh[4], kl[4];
    if (w < 4) {
#pragma unroll
        for (int mf = 0; mf < 4; ++mf) {
            const size_t kr = ((size_t)(b * HW + 16 * mf + lm)) * DQK + 8 * lg;
            kh[mf] = *(const bf16x8*)(kth + kr);
            kl[mf] = *(const bf16x8*)(ktl + kr);
        }
    }

    for (int jt = 0; jt < NT; ++jt) {
        const int j0  = jt * JB;
        const int buf = jt & 1;

        // PV A-frags (x rows, c = 32w+16cf+lm) — issued early, all waves
        bf16x8 afr[2][2];
#pragma unroll
        for (int cf = 0; cf < 2; ++cf)
#pragma unroll
            for (int ks = 0; ks < 2; ++ks)
                afr[cf][ks] = *(const bf16x8*)(xb +
                    (size_t)(32 * w + 16 * cf + lm) * HW + j0 + 32 * ks + 8 * lg);

        if (w < 4) {
            // scores from prefetched K-frags: 3 MFMAs per 16x16 frag
            f32x4 sc[4];
#pragma unroll
            for (int mf = 0; mf < 4; ++mf) {
                f32x4 z = (f32x4){0.f, 0.f, 0.f, 0.f};
                z = __builtin_amdgcn_mfma_f32_16x16x32_bf16(kh[mf], qh, z, 0, 0, 0);
                z = __builtin_amdgcn_mfma_f32_16x16x32_bf16(kl[mf], qh, z, 0, 0, 0);
                z = __builtin_amdgcn_mfma_f32_16x16x32_bf16(kh[mf], ql, z, 0, 0, 0);
                sc[mf] = z;
            }
            // prefetch next tile's K-frags (latency hidden by softmax below)
            const int jn = (jt + 1 < NT) ? j0 + JB : j0;
#pragma unroll
            for (int mf = 0; mf < 4; ++mf) {
                const size_t kr = ((size_t)(b * HW + jn + 16 * mf + lm)) * DQK + 8 * lg;
                kh[mf] = *(const bf16x8*)(kth + kr);
                kl[mf] = *(const bf16x8*)(ktl + kr);
            }
            // mask + row max IN PLACE (row i per lane; j over mf, r, lg)
            float pm = -INFINITY;
#pragma unroll
            for (int mf = 0; mf < 4; ++mf) {
                float4 mj = *(const float4*)&mb[j0 + 16 * mf + 4 * lg];
#pragma unroll
                for (int r = 0; r < 4; ++r) {
                    float mjr = (r == 0) ? mj.x : (r == 1) ? mj.y : (r == 2) ? mj.z : mj.w;
                    float mm = mi * mjr;
                    float v = (mm == 0.f) ? -INFINITY : sc[mf][r] * mm;
                    sc[mf][r] = v;
                    pm = fmaxf(pm, v);
                }
            }
            pm = fmaxf(pm, __shfl_xor(pm, 16));
            pm = fmaxf(pm, __shfl_xor(pm, 32));
            const float mnew = fmaxf(mreg, pm);
            const float fc   = __expf(mreg - mnew);   // first tile: exp(-inf)=0
            float psum = 0.f;
            const int swz = (lm & 7) << 3;            // i&7 == lm&7
#pragma unroll
            for (int mf = 0; mf < 4; ++mf) {
                float p0 = __expf(sc[mf][0] - mnew);
                float p1 = __expf(sc[mf][1] - mnew);
                float p2 = __expf(sc[mf][2] - mnew);
                float p3 = __expf(sc[mf][3] - mnew);
                psum += p0 + p1 + p2 + p3;
                *(ushort4*)&pbs[buf][(16 * ib + lm) * JB + ((16 * mf + 4 * lg) ^ swz)] =
                    make_ushort4(f2bf(p0), f2bf(p1), f2bf(p2), f2bf(p3));
            }
            psum += __shfl_xor(psum, 16);
            psum += __shfl_xor(psum, 32);
            lreg = lreg * fc + psum;
            mreg = mnew;
            if (lg == 0) fs2[buf][16 * ib + lm] = fc;
        }
        __syncthreads();

        // rescale (factor per acc column i = 16fi+lm)
        float fcol[4];
#pragma unroll
        for (int fi = 0; fi < 4; ++fi) fcol[fi] = fs2[buf][16 * fi + lm];
#pragma unroll
        for (int cf = 0; cf < 2; ++cf)
#pragma unroll
            for (int fi = 0; fi < 4; ++fi) acc[cf][fi] *= fcol[fi];

        // PV MFMAs
#pragma unroll
        for (int fi = 0; fi < 4; ++fi)
#pragma unroll
            for (int ks = 0; ks < 2; ++ks) {
                bf16x8 bfr = *(const bf16x8*)&pbs[buf][(16 * fi + lm) * JB +
                                ((32 * ks + 8 * lg) ^ ((lm & 7) << 3))];
#pragma unroll
                for (int cf = 0; cf < 2; ++cf)
                    acc[cf][fi] = __builtin_amdgcn_mfma_f32_16x16x32_bf16(
                        afr[cf][ks], bfr, acc[cf][fi], 0, 0, 0);
            }
    }

    if (w < 4 && lg == 0) lsb[16 * ib + lm] = lreg;
    __syncthreads();
    float linv[4];
#pragma unroll
    for (int fi = 0; fi < 4; ++fi) linv[fi] = 1.f / lsb[16 * fi + lm];
#pragma unroll
    for (int cf = 0; cf < 2; ++cf)
#pragma unroll
        for (int fi = 0; fi < 4; ++fi)
#pragma unroll
            for (int r = 0; r < 4; ++r) {
                const int c = 32 * w + 16 * cf + 4 * lg + r;
                attnx[((size_t)b * CCH + c) * HW + i0 + 16 * fi + lm] =
                    acc[cf][fi][r] * linv[fi];
            }
}

// ---------------------------------------------------------------------------
// K4: pre = Wov attnx + bov; o2 = gamma*pre + x; LayerNorm over channels.
// grid 512, block = 32 pixels x 8 out-groups of 32.
// ---------------------------------------------------------------------------
__global__ __launch_bounds__(256) void final2_kernel(
    const float* __restrict__ attnx, const float* __restrict__ Wov,
    const float* __restrict__ bov, const float* __restrict__ x,
    const float* __restrict__ gamma, const float* __restrict__ ln_w,
    const float* __restrict__ ln_b, float* __restrict__ out)
{
    const int t = threadIdx.x;
    const int p5 = t & 31;
    const int og = t >> 5;               // 0..7
    const int g0 = blockIdx.x * 32;
    const int b  = g0 >> 12;
    const int p  = (g0 & (HW - 1)) + p5;

    const float* ab = attnx + (size_t)b * CCH * HW + p;
    const float* xb = x + (size_t)b * CCH * HW + p;

    float acc[32];
#pragma unroll
    for (int oo = 0; oo < 32; ++oo) acc[oo] = bov[og * 32 + oo];

    for (int c0 = 0; c0 < CCH; c0 += 8) {
        float av[8];
#pragma unroll
        for (int cc = 0; cc < 8; ++cc) av[cc] = ab[(size_t)(c0 + cc) * HW];
#pragma unroll
        for (int oo = 0; oo < 32; ++oo)
#pragma unroll
            for (int cc = 0; cc < 8; ++cc)
                acc[oo] = fmaf(Wov[(og * 32 + oo) * CCH + c0 + cc], av[cc], acc[oo]);
    }

    const float gam = gamma[0];
    float s1 = 0.f, s2 = 0.f;
#pragma unroll
    for (int oo = 0; oo < 32; ++oo) {
        float v = fmaf(gam, acc[oo], xb[(size_t)(og * 32 + oo) * HW]);
        acc[oo] = v;
        s1 += v;
        s2 = fmaf(v, v, s2);
    }

    __shared__ float r1[8][32], r2[8][32];
    r1[og][p5] = s1;
    r2[og][p5] = s2;
    __syncthreads();
    if (og == 0) {
        float a = 0.f, q2 = 0.f;
#pragma unroll
        for (int gg = 0; gg < 8; ++gg) { a += r1[gg][p5]; q2 += r2[gg][p5]; }
        float mu  = a * (1.f / CCH);
        float var = q2 * (1.f / CCH) - mu * mu;
        r1[0][p5] = mu;
        r2[0][p5] = 1.f / sqrtf(var + 1e-5f);
    }
    __syncthreads();
    const float mu   = r1[0][p5];
    const float rstd = r2[0][p5];
#pragma unroll
    for (int oo = 0; oo < 32; ++oo) {
        const int o = og * 32 + oo;
        float v = (acc[oo] - mu) * rstd * ln_w[o] + ln_b[o];
        out[((size_t)b * CCH + o) * HW + p] = v;
    }
}

// ---------------------------------------------------------------------------
extern "C" void kernel_launch(void* const* d_in, const int* in_sizes, int n_in,
                              void* d_out, int out_size, void* d_ws, size_t ws_size,
                              hipStream_t stream)
{
    const float* x     = (const float*)d_in[0];
    const float* mask  = (const float*)d_in[1];
    const float* Wq    = (const float*)d_in[2];
    const float* bq    = (const float*)d_in[3];
    const float* Wk    = (const float*)d_in[4];
    const float* bk    = (const float*)d_in[5];
    const float* Wv    = (const float*)d_in[6];
    const float* bv    = (const float*)d_in[7];
    const float* Wo    = (const float*)d_in[8];
    const float* bo    = (const float*)d_in[9];
    const float* gamma = (const float*)d_in[10];
    const float* ln_w  = (const float*)d_in[11];
    const float* ln_b  = (const float*)d_in[12];
    float* out = (float*)d_out;

    // ws layout: qth|qtl|kth|ktl (bf16 [B*HW][32], 1MB each) | attnx f32 16MB
    //            | Wov 256KB | bov | xbf bf16 8MB   (~28.3 MB total)
    ushort* qth  = (ushort*)d_ws;
    ushort* qtl  = qth + (size_t)4 * HW * DQK;
    ushort* kth  = qtl + (size_t)4 * HW * DQK;
    ushort* ktl  = kth + (size_t)4 * HW * DQK;
    float* attnx = (float*)(ktl + (size_t)4 * HW * DQK);
    float* Wov   = attnx + (size_t)4 * CCH * HW;
    float* bov   = Wov + CCH * CCH;
    ushort* xbf  = (ushort*)(bov + 1024);

    x2bf_kernel<<<4096, 256, 0, stream>>>(x, xbf);
    qkhl_kernel<<<dim3(256, 2), 256, 0, stream>>>(x, Wq, bq, Wk, bk,
                                                  qth, qtl, kth, ktl);
    wov_kernel<<<256, 256, 0, stream>>>(Wo, Wv, bv, bo, Wov, bov);
    attn3_kernel<<<256, 512, 0, stream>>>(qth, qtl, kth, ktl, xbf, mask, attnx);
    final2_kernel<<<512, 256, 0, stream>>>(attnx, Wov, bov, x, gamma,
                                           ln_w, ln_b, out);
}